// Round 9
// baseline (232.861 us; speedup 1.0000x reference)
//
#include <hip/hip_runtime.h>
#include <hip/hip_bf16.h>
#include <math.h>

#define EMBED_DIM 1024
#define NUM_HEADS 16
#define HEAD_DIM 64
#define BATCH 2
#define SEQ 2048

using short8  = __attribute__((ext_vector_type(8))) short;
using floatx4 = __attribute__((ext_vector_type(4))) float;

__device__ __forceinline__ ushort f2bf(float f) {
    unsigned u = __float_as_uint(f);
    u = (u + 0x7FFFu + ((u >> 16) & 1u)) >> 16;   // RNE
    return (ushort)u;
}

// pack two floats to bf16x2 (half-up rounding — P values are in [0,1], fine)
__device__ __forceinline__ unsigned bfpack2(float a, float b) {
    return ((__float_as_uint(a) + 0x8000u) >> 16) |
           (((__float_as_uint(b) + 0x8000u) >> 16) << 16);
}

// async global->LDS, 16B per lane; LDS dest = wave-uniform base + lane*16.
__device__ __forceinline__ void load_lds16(const ushort* g, ushort* l) {
    __builtin_amdgcn_global_load_lds(
        (const __attribute__((address_space(1))) void*)g,
        (__attribute__((address_space(3))) void*)l, 16, 0, 0);
}

// ---------------------------------------------------------------------------
// Fused prep: cast x -> bf16, transpose+cast W_qkv and W_out.
// ---------------------------------------------------------------------------
__device__ __forceinline__ void tc_tile(
    const float* __restrict__ W, ushort* __restrict__ Wt,
    int K, int N, int n0, int k0, float (*t)[65])
{
    const int c = threadIdx.x & 63, r0 = (threadIdx.x >> 6) * 16;
    #pragma unroll
    for (int r = 0; r < 16; ++r)
        t[r0 + r][c] = W[(size_t)(k0 + r0 + r) * N + n0 + c];
    __syncthreads();
    #pragma unroll
    for (int r = 0; r < 16; ++r)
        Wt[(size_t)(n0 + r0 + r) * K + k0 + c] = f2bf(t[c][r0 + r]);
}

__global__ __launch_bounds__(256) void prep_all(
    const float* __restrict__ x, const float* __restrict__ W_qkv,
    const float* __restrict__ W_out,
    ushort* __restrict__ xb, ushort* __restrict__ Wqb_t, ushort* __restrict__ Wob_t)
{
    __shared__ float t[64][65];
    const int bx = blockIdx.x;
    if (bx < 4096) {
        int i = (bx * 256 + threadIdx.x) * 4;
        float4 v = *(const float4*)&x[i];
        ushort4 o = { f2bf(v.x), f2bf(v.y), f2bf(v.z), f2bf(v.w) };
        *(ushort4*)&xb[i] = o;
    } else if (bx < 4096 + 768) {
        int b = bx - 4096;
        tc_tile(W_qkv, Wqb_t, 1024, 3072, (b % 48) * 64, (b / 48) * 64, t);
    } else {
        int b = bx - 4864;
        tc_tile(W_out, Wob_t, 1024, 1024, (b % 16) * 64, (b / 16) * 64, t);
    }
}

// ---------------------------------------------------------------------------
// bf16 MFMA GEMM core, double-buffered, FRAGMENT-ORDERED LDS.
// LDS tile = 8 chunks of 1 KB; chunk c holds rows [c*16, c*16+16) in MFMA
// fragment order: lane l's 16 B at c*1024 + l*16 <-> A[c*16+(l&15)][(l>>4)*8..+8].
// ds_read addresses are conflict-free (lane*16 covers all 32 banks) and
// k-loop-invariant. Issue-early prefetch, one barrier per K-step.
// ---------------------------------------------------------------------------
#define GK 1024

__device__ __forceinline__ void gemm_core(
    const ushort* __restrict__ A, const ushort* __restrict__ Bt,
    int m0, int n0, ushort* As0, ushort* As1, ushort* Bs0, ushort* Bs1,
    floatx4 acc[4][4])
{
    const int tid  = threadIdx.x;
    const int w    = tid >> 6;
    const int lane = tid & 63;
    const int col  = lane & 15;
    const int quad = lane >> 4;
    const int wm   = w >> 1, wn = w & 1;

    #pragma unroll
    for (int i = 0; i < 4; ++i)
        #pragma unroll
        for (int j = 0; j < 4; ++j)
            acc[i][j] = (floatx4){0.f, 0.f, 0.f, 0.f};

    // wave w stages chunks 2w, 2w+1 (rows 32w..32w+31), gather per lane
    const ushort* ga[2];
    const ushort* gb[2];
    #pragma unroll
    for (int t = 0; t < 2; ++t) {
        const int c = 2 * w + t;
        ga[t] = A  + (size_t)(m0 + c * 16 + col) * GK + quad * 8;
        gb[t] = Bt + (size_t)(n0 + c * 16 + col) * GK + quad * 8;
    }

    // prologue: stage k=0 into buffer 0
    #pragma unroll
    for (int t = 0; t < 2; ++t) {
        load_lds16(ga[t], As0 + (2 * w + t) * 512);
        load_lds16(gb[t], Bs0 + (2 * w + t) * 512);
    }
    __syncthreads();

    for (int k0 = 0; k0 < GK; k0 += 32) {
        const int cur = (k0 >> 5) & 1;
        const ushort* Ac = cur ? As1 : As0;
        const ushort* Bc = cur ? Bs1 : Bs0;
        ushort* An = cur ? As0 : As1;
        ushort* Bn = cur ? Bs0 : Bs1;

        if (k0 + 32 < GK) {   // issue prefetch BEFORE compute
            #pragma unroll
            for (int t = 0; t < 2; ++t) {
                load_lds16(ga[t] + k0 + 32, An + (2 * w + t) * 512);
                load_lds16(gb[t] + k0 + 32, Bn + (2 * w + t) * 512);
            }
        }

        short8 af[4], bf[4];
        #pragma unroll
        for (int i = 0; i < 4; ++i)
            af[i] = *(const short8*)&Ac[(wm * 4 + i) * 512 + lane * 8];
        #pragma unroll
        for (int j = 0; j < 4; ++j)
            bf[j] = *(const short8*)&Bc[(wn * 4 + j) * 512 + lane * 8];
        #pragma unroll
        for (int i = 0; i < 4; ++i)
            #pragma unroll
            for (int j = 0; j < 4; ++j)
                acc[i][j] = __builtin_amdgcn_mfma_f32_16x16x32_bf16(af[i], bf[j], acc[i][j], 0, 0, 0);

        __syncthreads();   // prefetch landed (covered by the MFMAs above)
    }
}

// GEMM1: qkv projection; fused split/cast; V emitted transposed.
__global__ __launch_bounds__(256) void gemm_qkv_mfma(
    const ushort* __restrict__ A, const ushort* __restrict__ Bt,
    const float* __restrict__ bias,
    ushort* __restrict__ Qb, ushort* __restrict__ Kb, ushort* __restrict__ Vt)
{
    __shared__ __align__(16) ushort As[2][128 * 32];
    __shared__ __align__(16) ushort Bs[2][128 * 32];
    const int n0 = blockIdx.x * 128;
    const int m0 = blockIdx.y * 128;

    floatx4 acc[4][4];
    gemm_core(A, Bt, m0, n0, As[0], As[1], Bs[0], Bs[1], acc);

    const int lane = threadIdx.x & 63;
    const int w    = threadIdx.x >> 6;
    const int col  = lane & 15, quad = lane >> 4;
    const int wm   = w >> 1, wn = w & 1;

    #pragma unroll
    for (int j = 0; j < 4; ++j) {
        const int n = n0 + wn * 64 + j * 16 + col;
        const float bj = bias[n];
        const int part = n >> 10;
        const int h = (n >> 6) & 15;
        const int d = n & 63;
        #pragma unroll
        for (int i = 0; i < 4; ++i)
            #pragma unroll
            for (int r = 0; r < 4; ++r) {
                const int m = m0 + wm * 64 + i * 16 + quad * 4 + r;
                const int b = m >> 11, s = m & 2047;
                const int bh = b * 16 + h;
                const ushort bv = f2bf(acc[i][j][r] + bj);
                if (part == 0)      Qb[((size_t)bh * SEQ + s) * 64 + d] = bv;
                else if (part == 1) Kb[((size_t)bh * SEQ + s) * 64 + d] = bv;
                else                Vt[((size_t)bh * 64 + d) * SEQ + s] = bv;
            }
    }
}

// GEMM2: out = attn_b @ W_out + b_out -> fp32
__global__ __launch_bounds__(256) void gemm_out_mfma(
    const ushort* __restrict__ A, const ushort* __restrict__ Bt,
    const float* __restrict__ bias, float* __restrict__ out)
{
    __shared__ __align__(16) ushort As[2][128 * 32];
    __shared__ __align__(16) ushort Bs[2][128 * 32];
    const int n0 = blockIdx.x * 128;
    const int m0 = blockIdx.y * 128;

    floatx4 acc[4][4];
    gemm_core(A, Bt, m0, n0, As[0], As[1], Bs[0], Bs[1], acc);

    const int lane = threadIdx.x & 63;
    const int w    = threadIdx.x >> 6;
    const int col  = lane & 15, quad = lane >> 4;
    const int wm   = w >> 1, wn = w & 1;

    #pragma unroll
    for (int j = 0; j < 4; ++j) {
        const int n = n0 + wn * 64 + j * 16 + col;
        const float bj = bias[n];
        #pragma unroll
        for (int i = 0; i < 4; ++i)
            #pragma unroll
            for (int r = 0; r < 4; ++r) {
                const int m = m0 + wm * 64 + i * 16 + quad * 4 + r;
                out[(size_t)m * EMBED_DIM + n] = acc[i][j][r] + bj;
            }
    }
}

// ---------------------------------------------------------------------------
// Flash attention, bf16 MFMA. 128-query block, 32 queries per wave.
// K/V LDS chunk mapping (round-7 verified): chunk c = blk*2 + half holds
//   lane l -> row (c>>1)*16 + (l&15), dims (c&1)*32 + (l>>4)*8 .. +8
// (rows = keys for K, d for V^T; dims = head-dim for K, keys for V^T).
// Round 8's bug: staging used the GEMM mapping (rows c*16+col, dims quad*8),
// which for V indexed d up to 127 — past the 64-d extent (OOB into next head).
// Q fragments in registers; S^T = K·Q^T; no running max; dbuf issue-early
// prefetch, one barrier per key-tile; LPT order.
// ---------------------------------------------------------------------------
#define LP 72

__global__ __launch_bounds__(256) void attn_fused(
    const ushort* __restrict__ Qb, const ushort* __restrict__ Kb,
    const ushort* __restrict__ Vt, ushort* __restrict__ out)
{
    const int id = blockIdx.x;
    const int qt = 15 - (id >> 5);          // 128-q tiles, reversed (LPT)
    const int bh = id & 31;
    const int b  = bh >> 4, h = bh & 15;
    const int q0 = qt * 128;
    const int nkt = qt * 2 + 2;             // 64-key tiles covering q0+127

    __shared__ __align__(16) ushort Ks[2][8 * 512];   // 16 KB dbuf
    __shared__ __align__(16) ushort Vs[2][8 * 512];   // 16 KB dbuf
    __shared__ __align__(16) ushort Ps[128 * LP];     // 18 KB
    __shared__ __align__(16) float  ls[4][2][16];

    const int tid  = threadIdx.x;
    const int w    = tid >> 6;
    const int lane = tid & 63;
    const int col  = lane & 15;
    const int quad = lane >> 4;
    const int qbase = w * 32;               // wave's first local query

    // ---- Q fragments -> registers (loop-invariant B operands) ----
    short8 qf[2][2];
    #pragma unroll
    for (int qg = 0; qg < 2; ++qg)
        #pragma unroll
        for (int kh = 0; kh < 2; ++kh)
            qf[qg][kh] = *(const short8*)&Qb[((size_t)bh * SEQ + q0 + qbase + qg * 16 + col) * 64
                                             + kh * 32 + quad * 8];

    // ---- K/V staging pointers: wave w stages chunks 2w, 2w+1 ----
    //   chunk 2w+t: row w*16+col, dims t*32+quad*8   (round-7 mapping)
    const ushort* kg[2];
    const ushort* vg[2];
    #pragma unroll
    for (int t = 0; t < 2; ++t) {
        kg[t] = Kb + (size_t)bh * SEQ * 64 + (size_t)(w * 16 + col) * 64 + t * 32 + quad * 8;
        vg[t] = Vt + (size_t)bh * 64 * SEQ + (size_t)(w * 16 + col) * SEQ + t * 32 + quad * 8;
    }

    // prologue: stage tile 0 into buffer 0
    #pragma unroll
    for (int t = 0; t < 2; ++t) {
        load_lds16(kg[t], &Ks[0][(2 * w + t) * 512]);
        load_lds16(vg[t], &Vs[0][(2 * w + t) * 512]);
        kg[t] += 64 * 64;
        vg[t] += 64;
    }
    __syncthreads();

    floatx4 acc_o[4][2];
    #pragma unroll
    for (int dbi = 0; dbi < 4; ++dbi)
        #pragma unroll
        for (int qg = 0; qg < 2; ++qg)
            acc_o[dbi][qg] = (floatx4){0.f, 0.f, 0.f, 0.f};
    float l_lane[2] = {0.f, 0.f};

    for (int kt = 0; kt < nkt; ++kt) {
        const int cur = kt & 1;
        const ushort* Kc = Ks[cur];
        const ushort* Vc = Vs[cur];
        const int k0g = kt * 64;

        if (kt + 1 < nkt) {   // issue-early prefetch into the other buffer
            ushort* Kn = (ushort*)Ks[cur ^ 1];
            ushort* Vn = (ushort*)Vs[cur ^ 1];
            #pragma unroll
            for (int t = 0; t < 2; ++t) {
                load_lds16(kg[t], &Kn[(2 * w + t) * 512]);
                load_lds16(vg[t], &Vn[(2 * w + t) * 512]);
                kg[t] += 64 * 64;
                vg[t] += 64;
            }
        }

        // ---- S^T = K Q^T : 64 keys x 32 queries per wave ----
        floatx4 st[4][2];
        #pragma unroll
        for (int kb = 0; kb < 4; ++kb) {
            short8 k0f = *(const short8*)&Kc[(kb * 2 + 0) * 512 + lane * 8];
            short8 k1f = *(const short8*)&Kc[(kb * 2 + 1) * 512 + lane * 8];
            #pragma unroll
            for (int qg = 0; qg < 2; ++qg) {
                floatx4 z = (floatx4){0.f, 0.f, 0.f, 0.f};
                z = __builtin_amdgcn_mfma_f32_16x16x32_bf16(k0f, qf[qg][0], z, 0, 0, 0);
                z = __builtin_amdgcn_mfma_f32_16x16x32_bf16(k1f, qf[qg][1], z, 0, 0, 0);
                st[kb][qg] = z;   // lane: query col; regs: keys kb*16+quad*4+r
            }
        }

        // ---- p = exp(s/8); write P rows (ds_write_b64) ----
        #pragma unroll
        for (int qg = 0; qg < 2; ++qg) {
            const int qmin = q0 + qbase + qg * 16;      // lowest query in group
            ushort* prow = &Ps[(qbase + qg * 16 + col) * LP];
            if (k0g + 63 <= qmin) {                     // no-mask fast path
                #pragma unroll
                for (int kb = 0; kb < 4; ++kb) {
                    float p[4];
                    #pragma unroll
                    for (int r = 0; r < 4; ++r) {
                        p[r] = __expf(st[kb][qg][r] * 0.125f);
                        l_lane[qg] += p[r];
                    }
                    uint2 u = { bfpack2(p[0], p[1]), bfpack2(p[2], p[3]) };
                    *(uint2*)&prow[kb * 16 + quad * 4] = u;
                }
            } else {                                    // diagonal zone
                const int qg_g = qmin + col;            // this lane's query
                #pragma unroll
                for (int kb = 0; kb < 4; ++kb) {
                    const int kbase = k0g + kb * 16 + quad * 4;
                    float p[4];
                    #pragma unroll
                    for (int r = 0; r < 4; ++r) {
                        float e = __expf(st[kb][qg][r] * 0.125f);
                        p[r] = (kbase + r > qg_g) ? 0.f : e;
                        l_lane[qg] += p[r];
                    }
                    uint2 u = { bfpack2(p[0], p[1]), bfpack2(p[2], p[3]) };
                    *(uint2*)&prow[kb * 16 + quad * 4] = u;
                }
            }
        }

        // ---- O += P V  (Ps rows wave-private; in-wave LDS dep only) ----
        short8 pa[2][2];
        #pragma unroll
        for (int qg = 0; qg < 2; ++qg)
            #pragma unroll
            for (int kh = 0; kh < 2; ++kh)
                pa[qg][kh] = *(const short8*)&Ps[(qbase + qg * 16 + col) * LP + kh * 32 + quad * 8];
        #pragma unroll
        for (int dbi = 0; dbi < 4; ++dbi) {
            short8 vb0 = *(const short8*)&Vc[(dbi * 2 + 0) * 512 + lane * 8];
            short8 vb1 = *(const short8*)&Vc[(dbi * 2 + 1) * 512 + lane * 8];
            #pragma unroll
            for (int qg = 0; qg < 2; ++qg) {
                acc_o[dbi][qg] = __builtin_amdgcn_mfma_f32_16x16x32_bf16(pa[qg][0], vb0, acc_o[dbi][qg], 0, 0, 0);
                acc_o[dbi][qg] = __builtin_amdgcn_mfma_f32_16x16x32_bf16(pa[qg][1], vb1, acc_o[dbi][qg], 0, 0, 0);
            }
        }

        __syncthreads();   // prefetch landed (covered by compute above)
    }

    // ---- finalize l (reduce the 4 quads sharing each query column) ----
    #pragma unroll
    for (int qg = 0; qg < 2; ++qg) {
        float lr = l_lane[qg];
        lr += __shfl_xor(lr, 16);
        lr += __shfl_xor(lr, 32);
        if (quad == 0) ls[w][qg][col] = 1.f / lr;   // wave-private
    }

    #pragma unroll
    for (int qg = 0; qg < 2; ++qg) {
        float4 invv = *(const float4*)&ls[w][qg][quad * 4];
        #pragma unroll
        for (int dbi = 0; dbi < 4; ++dbi)
            #pragma unroll
            for (int r = 0; r < 4; ++r) {
                int q = q0 + qbase + qg * 16 + quad * 4 + r;
                int d = dbi * 16 + col;
                float inv = (r == 0) ? invv.x : (r == 1) ? invv.y : (r == 2) ? invv.z : invv.w;
                out[((size_t)(b * SEQ + q)) * EMBED_DIM + h * 64 + d] = f2bf(acc_o[dbi][qg][r] * inv);
            }
    }
}

// ---------------------------------------------------------------------------
extern "C" void kernel_launch(void* const* d_in, const int* in_sizes, int n_in,
                              void* d_out, int out_size, void* d_ws, size_t ws_size,
                              hipStream_t stream)
{
    const float* x     = (const float*)d_in[0];
    const float* W_qkv = (const float*)d_in[1];
    const float* b_qkv = (const float*)d_in[2];
    const float* W_out = (const float*)d_in[3];
    const float* b_out = (const float*)d_in[4];
    float* out = (float*)d_out;

    const int M  = BATCH * SEQ;            // 4096
    const int D  = EMBED_DIM;              // 1024
    const int N1 = 3 * D;                  // 3072
    const size_t HE = (size_t)BATCH * NUM_HEADS * SEQ * 64;  // 4M

    ushort* xb    = (ushort*)d_ws;
    ushort* Wqb_t = xb + (size_t)M * D;
    ushort* Wob_t = Wqb_t + (size_t)D * N1;
    ushort* Qb    = Wob_t + (size_t)D * D;
    ushort* Kb    = Qb + HE;
    ushort* Vt    = Kb + HE;
    ushort* attnb = Vt + HE;

    // 0) fused prep: cast x, transpose+cast weights
    prep_all<<<5120, 256, 0, stream>>>(x, W_qkv, W_out, xb, Wqb_t, Wob_t);

    // 1) qkv projection
    gemm_qkv_mfma<<<dim3(N1 / 128, M / 128), 256, 0, stream>>>(
        xb, Wqb_t, b_qkv, Qb, Kb, Vt);

    // 2) flash attention (128-q blocks)
    attn_fused<<<dim3(16 * 32), 256, 0, stream>>>(Qb, Kb, Vt, attnb);

    // 3) output projection
    gemm_out_mfma<<<dim3(D / 128, M / 128), 256, 0, stream>>>(
        attnb, Wob_t, b_out, out);
}

// Round 10
// 208.026 us; speedup vs baseline: 1.1194x; 1.1194x over previous
//
#include <hip/hip_runtime.h>
#include <hip/hip_bf16.h>
#include <math.h>

#define EMBED_DIM 1024
#define NUM_HEADS 16
#define HEAD_DIM 64
#define BATCH 2
#define SEQ 2048

using short8  = __attribute__((ext_vector_type(8))) short;
using floatx4 = __attribute__((ext_vector_type(4))) float;

__device__ __forceinline__ ushort f2bf(float f) {
    unsigned u = __float_as_uint(f);
    u = (u + 0x7FFFu + ((u >> 16) & 1u)) >> 16;   // RNE
    return (ushort)u;
}

// pack two floats to bf16x2 (half-up rounding — P values are in [0,1], fine)
__device__ __forceinline__ unsigned bfpack2(float a, float b) {
    return ((__float_as_uint(a) + 0x8000u) >> 16) |
           (((__float_as_uint(b) + 0x8000u) >> 16) << 16);
}

// async global->LDS, 16B per lane; LDS dest = wave-uniform base + lane*16.
__device__ __forceinline__ void load_lds16(const ushort* g, ushort* l) {
    __builtin_amdgcn_global_load_lds(
        (const __attribute__((address_space(1))) void*)g,
        (__attribute__((address_space(3))) void*)l, 16, 0, 0);
}

// ---------------------------------------------------------------------------
// Fused prep: cast x -> bf16, transpose+cast W_qkv and W_out.
// ---------------------------------------------------------------------------
__device__ __forceinline__ void tc_tile(
    const float* __restrict__ W, ushort* __restrict__ Wt,
    int K, int N, int n0, int k0, float (*t)[65])
{
    const int c = threadIdx.x & 63, r0 = (threadIdx.x >> 6) * 16;
    #pragma unroll
    for (int r = 0; r < 16; ++r)
        t[r0 + r][c] = W[(size_t)(k0 + r0 + r) * N + n0 + c];
    __syncthreads();
    #pragma unroll
    for (int r = 0; r < 16; ++r)
        Wt[(size_t)(n0 + r0 + r) * K + k0 + c] = f2bf(t[c][r0 + r]);
}

__global__ __launch_bounds__(256) void prep_all(
    const float* __restrict__ x, const float* __restrict__ W_qkv,
    const float* __restrict__ W_out,
    ushort* __restrict__ xb, ushort* __restrict__ Wqb_t, ushort* __restrict__ Wob_t)
{
    __shared__ float t[64][65];
    const int bx = blockIdx.x;
    if (bx < 4096) {
        int i = (bx * 256 + threadIdx.x) * 4;
        float4 v = *(const float4*)&x[i];
        ushort4 o = { f2bf(v.x), f2bf(v.y), f2bf(v.z), f2bf(v.w) };
        *(ushort4*)&xb[i] = o;
    } else if (bx < 4096 + 768) {
        int b = bx - 4096;
        tc_tile(W_qkv, Wqb_t, 1024, 3072, (b % 48) * 64, (b / 48) * 64, t);
    } else {
        int b = bx - 4864;
        tc_tile(W_out, Wob_t, 1024, 1024, (b % 16) * 64, (b / 16) * 64, t);
    }
}

// ---------------------------------------------------------------------------
// bf16 MFMA GEMM core, double-buffered, m97-style ROW-LINEAR staging.
// (Round-9 lesson: fragment-ordered gather staging scatters the wave's global
// addresses into 64x16B segments and tanks VMEM issue (48.5 -> 64.5 us);
// m97's row-linear staging (16 x 64B contiguous segments/wave) is faster even
// though its LDS fragment reads carry ~3.1M bank conflicts. Coalescing wins.)
// Issue-early prefetch: loads for k-step t+1 issued BEFORE computing step t.
// ---------------------------------------------------------------------------
#define GK 1024

__device__ __forceinline__ void gemm_core(
    const ushort* __restrict__ A, const ushort* __restrict__ Bt,
    int m0, int n0, ushort* As0, ushort* As1, ushort* Bs0, ushort* Bs1,
    floatx4 acc[4][4])
{
    const int tid  = threadIdx.x;
    const int w    = tid >> 6;
    const int lane = tid & 63;
    const int col  = lane & 15;
    const int quad = lane >> 4;
    const int wm   = w >> 1, wn = w & 1;

    #pragma unroll
    for (int i = 0; i < 4; ++i)
        #pragma unroll
        for (int j = 0; j < 4; ++j)
            acc[i][j] = (floatx4){0.f, 0.f, 0.f, 0.f};

    const int o0   = w * 2048 + lane * 16;   // byte offset in 8KB tile
    const int row0 = o0 >> 6;
    const int ke0  = (o0 & 63) >> 1;
    const int loff = (w * 2048) >> 1;        // LDS element offset for this wave

    const ushort* ga = A  + (size_t)(m0 + row0) * GK + ke0;
    const ushort* gb = Bt + (size_t)(n0 + row0) * GK + ke0;

    // prologue: stage k=0 into buffer 0
    #pragma unroll
    for (int t = 0; t < 2; ++t) {
        load_lds16(ga + (size_t)t * 16 * GK, As0 + loff + t * 512);
        load_lds16(gb + (size_t)t * 16 * GK, Bs0 + loff + t * 512);
    }
    __syncthreads();

    for (int k0 = 0; k0 < GK; k0 += 32) {
        const int cur = (k0 >> 5) & 1;
        ushort* Ac = cur ? As1 : As0;
        ushort* Bc = cur ? Bs1 : Bs0;
        ushort* An = cur ? As0 : As1;
        ushort* Bn = cur ? Bs0 : Bs1;

        if (k0 + 32 < GK) {   // issue prefetch BEFORE compute
            #pragma unroll
            for (int t = 0; t < 2; ++t) {
                load_lds16(ga + (k0 + 32) + (size_t)t * 16 * GK, An + loff + t * 512);
                load_lds16(gb + (k0 + 32) + (size_t)t * 16 * GK, Bn + loff + t * 512);
            }
        }

        short8 af[4], bf[4];
        #pragma unroll
        for (int i = 0; i < 4; ++i)
            af[i] = *(const short8*)&Ac[(wm * 64 + i * 16 + col) * 32 + quad * 8];
        #pragma unroll
        for (int j = 0; j < 4; ++j)
            bf[j] = *(const short8*)&Bc[(wn * 64 + j * 16 + col) * 32 + quad * 8];
        #pragma unroll
        for (int i = 0; i < 4; ++i)
            #pragma unroll
            for (int j = 0; j < 4; ++j)
                acc[i][j] = __builtin_amdgcn_mfma_f32_16x16x32_bf16(af[i], bf[j], acc[i][j], 0, 0, 0);

        __syncthreads();   // prefetch landed (covered by the MFMAs above)
    }
}

// GEMM1: qkv projection; fused split/cast; V emitted transposed.
__global__ __launch_bounds__(256) void gemm_qkv_mfma(
    const ushort* __restrict__ A, const ushort* __restrict__ Bt,
    const float* __restrict__ bias,
    ushort* __restrict__ Qb, ushort* __restrict__ Kb, ushort* __restrict__ Vt)
{
    __shared__ __align__(16) ushort As[2][128 * 32];
    __shared__ __align__(16) ushort Bs[2][128 * 32];
    const int n0 = blockIdx.x * 128;
    const int m0 = blockIdx.y * 128;

    floatx4 acc[4][4];
    gemm_core(A, Bt, m0, n0, As[0], As[1], Bs[0], Bs[1], acc);

    const int lane = threadIdx.x & 63;
    const int w    = threadIdx.x >> 6;
    const int col  = lane & 15, quad = lane >> 4;
    const int wm   = w >> 1, wn = w & 1;

    #pragma unroll
    for (int j = 0; j < 4; ++j) {
        const int n = n0 + wn * 64 + j * 16 + col;
        const float bj = bias[n];
        const int part = n >> 10;
        const int h = (n >> 6) & 15;
        const int d = n & 63;
        #pragma unroll
        for (int i = 0; i < 4; ++i)
            #pragma unroll
            for (int r = 0; r < 4; ++r) {
                const int m = m0 + wm * 64 + i * 16 + quad * 4 + r;
                const int b = m >> 11, s = m & 2047;
                const int bh = b * 16 + h;
                const ushort bv = f2bf(acc[i][j][r] + bj);
                if (part == 0)      Qb[((size_t)bh * SEQ + s) * 64 + d] = bv;
                else if (part == 1) Kb[((size_t)bh * SEQ + s) * 64 + d] = bv;
                else                Vt[((size_t)bh * 64 + d) * SEQ + s] = bv;
            }
    }
}

// GEMM2: out = attn_b @ W_out + b_out -> fp32
__global__ __launch_bounds__(256) void gemm_out_mfma(
    const ushort* __restrict__ A, const ushort* __restrict__ Bt,
    const float* __restrict__ bias, float* __restrict__ out)
{
    __shared__ __align__(16) ushort As[2][128 * 32];
    __shared__ __align__(16) ushort Bs[2][128 * 32];
    const int n0 = blockIdx.x * 128;
    const int m0 = blockIdx.y * 128;

    floatx4 acc[4][4];
    gemm_core(A, Bt, m0, n0, As[0], As[1], Bs[0], Bs[1], acc);

    const int lane = threadIdx.x & 63;
    const int w    = threadIdx.x >> 6;
    const int col  = lane & 15, quad = lane >> 4;
    const int wm   = w >> 1, wn = w & 1;

    #pragma unroll
    for (int j = 0; j < 4; ++j) {
        const int n = n0 + wn * 64 + j * 16 + col;
        const float bj = bias[n];
        #pragma unroll
        for (int i = 0; i < 4; ++i)
            #pragma unroll
            for (int r = 0; r < 4; ++r) {
                const int m = m0 + wm * 64 + i * 16 + quad * 4 + r;
                out[(size_t)m * EMBED_DIM + n] = acc[i][j][r] + bj;
            }
    }
}

// ---------------------------------------------------------------------------
// Flash attention, bf16 MFMA. 128-query block, 32 queries per wave.
// (Round-9 verified correct.) K/V LDS chunk mapping: chunk c = blk*2 + half:
//   lane l -> row (c>>1)*16 + (l&15), dims (c&1)*32 + (l>>4)*8 .. +8
// K-row gather spans only 2 KB (rows 128 B apart) so coalescing stays OK.
// Q fragments in registers; S^T = K·Q^T; no running max; dbuf issue-early
// prefetch, one barrier per key-tile; LPT order.
// ---------------------------------------------------------------------------
#define LP 72

__global__ __launch_bounds__(256) void attn_fused(
    const ushort* __restrict__ Qb, const ushort* __restrict__ Kb,
    const ushort* __restrict__ Vt, ushort* __restrict__ out)
{
    const int id = blockIdx.x;
    const int qt = 15 - (id >> 5);          // 128-q tiles, reversed (LPT)
    const int bh = id & 31;
    const int b  = bh >> 4, h = bh & 15;
    const int q0 = qt * 128;
    const int nkt = qt * 2 + 2;             // 64-key tiles covering q0+127

    __shared__ __align__(16) ushort Ks[2][8 * 512];   // 16 KB dbuf
    __shared__ __align__(16) ushort Vs[2][8 * 512];   // 16 KB dbuf
    __shared__ __align__(16) ushort Ps[128 * LP];     // 18 KB
    __shared__ __align__(16) float  ls[4][2][16];

    const int tid  = threadIdx.x;
    const int w    = tid >> 6;
    const int lane = tid & 63;
    const int col  = lane & 15;
    const int quad = lane >> 4;
    const int qbase = w * 32;               // wave's first local query

    // ---- Q fragments -> registers (loop-invariant B operands) ----
    short8 qf[2][2];
    #pragma unroll
    for (int qg = 0; qg < 2; ++qg)
        #pragma unroll
        for (int kh = 0; kh < 2; ++kh)
            qf[qg][kh] = *(const short8*)&Qb[((size_t)bh * SEQ + q0 + qbase + qg * 16 + col) * 64
                                             + kh * 32 + quad * 8];

    // ---- K/V staging pointers: wave w stages chunks 2w, 2w+1 ----
    //   chunk 2w+t: row w*16+col, dims t*32+quad*8
    const ushort* kg[2];
    const ushort* vg[2];
    #pragma unroll
    for (int t = 0; t < 2; ++t) {
        kg[t] = Kb + (size_t)bh * SEQ * 64 + (size_t)(w * 16 + col) * 64 + t * 32 + quad * 8;
        vg[t] = Vt + (size_t)bh * 64 * SEQ + (size_t)(w * 16 + col) * SEQ + t * 32 + quad * 8;
    }

    // prologue: stage tile 0 into buffer 0
    #pragma unroll
    for (int t = 0; t < 2; ++t) {
        load_lds16(kg[t], &Ks[0][(2 * w + t) * 512]);
        load_lds16(vg[t], &Vs[0][(2 * w + t) * 512]);
        kg[t] += 64 * 64;
        vg[t] += 64;
    }
    __syncthreads();

    floatx4 acc_o[4][2];
    #pragma unroll
    for (int dbi = 0; dbi < 4; ++dbi)
        #pragma unroll
        for (int qg = 0; qg < 2; ++qg)
            acc_o[dbi][qg] = (floatx4){0.f, 0.f, 0.f, 0.f};
    float l_lane[2] = {0.f, 0.f};

    for (int kt = 0; kt < nkt; ++kt) {
        const int cur = kt & 1;
        const ushort* Kc = Ks[cur];
        const ushort* Vc = Vs[cur];
        const int k0g = kt * 64;

        if (kt + 1 < nkt) {   // issue-early prefetch into the other buffer
            ushort* Kn = (ushort*)Ks[cur ^ 1];
            ushort* Vn = (ushort*)Vs[cur ^ 1];
            #pragma unroll
            for (int t = 0; t < 2; ++t) {
                load_lds16(kg[t], &Kn[(2 * w + t) * 512]);
                load_lds16(vg[t], &Vn[(2 * w + t) * 512]);
                kg[t] += 64 * 64;
                vg[t] += 64;
            }
        }

        // ---- S^T = K Q^T : 64 keys x 32 queries per wave ----
        floatx4 st[4][2];
        #pragma unroll
        for (int kb = 0; kb < 4; ++kb) {
            short8 k0f = *(const short8*)&Kc[(kb * 2 + 0) * 512 + lane * 8];
            short8 k1f = *(const short8*)&Kc[(kb * 2 + 1) * 512 + lane * 8];
            #pragma unroll
            for (int qg = 0; qg < 2; ++qg) {
                floatx4 z = (floatx4){0.f, 0.f, 0.f, 0.f};
                z = __builtin_amdgcn_mfma_f32_16x16x32_bf16(k0f, qf[qg][0], z, 0, 0, 0);
                z = __builtin_amdgcn_mfma_f32_16x16x32_bf16(k1f, qf[qg][1], z, 0, 0, 0);
                st[kb][qg] = z;   // lane: query col; regs: keys kb*16+quad*4+r
            }
        }

        // ---- p = exp(s/8); write P rows (ds_write_b64) ----
        #pragma unroll
        for (int qg = 0; qg < 2; ++qg) {
            const int qmin = q0 + qbase + qg * 16;      // lowest query in group
            ushort* prow = &Ps[(qbase + qg * 16 + col) * LP];
            if (k0g + 63 <= qmin) {                     // no-mask fast path
                #pragma unroll
                for (int kb = 0; kb < 4; ++kb) {
                    float p[4];
                    #pragma unroll
                    for (int r = 0; r < 4; ++r) {
                        p[r] = __expf(st[kb][qg][r] * 0.125f);
                        l_lane[qg] += p[r];
                    }
                    uint2 u = { bfpack2(p[0], p[1]), bfpack2(p[2], p[3]) };
                    *(uint2*)&prow[kb * 16 + quad * 4] = u;
                }
            } else {                                    // diagonal zone
                const int qg_g = qmin + col;            // this lane's query
                #pragma unroll
                for (int kb = 0; kb < 4; ++kb) {
                    const int kbase = k0g + kb * 16 + quad * 4;
                    float p[4];
                    #pragma unroll
                    for (int r = 0; r < 4; ++r) {
                        float e = __expf(st[kb][qg][r] * 0.125f);
                        p[r] = (kbase + r > qg_g) ? 0.f : e;
                        l_lane[qg] += p[r];
                    }
                    uint2 u = { bfpack2(p[0], p[1]), bfpack2(p[2], p[3]) };
                    *(uint2*)&prow[kb * 16 + quad * 4] = u;
                }
            }
        }

        // ---- O += P V  (Ps rows wave-private; in-wave LDS dep only) ----
        short8 pa[2][2];
        #pragma unroll
        for (int qg = 0; qg < 2; ++qg)
            #pragma unroll
            for (int kh = 0; kh < 2; ++kh)
                pa[qg][kh] = *(const short8*)&Ps[(qbase + qg * 16 + col) * LP + kh * 32 + quad * 8];
        #pragma unroll
        for (int dbi = 0; dbi < 4; ++dbi) {
            short8 vb0 = *(const short8*)&Vc[(dbi * 2 + 0) * 512 + lane * 8];
            short8 vb1 = *(const short8*)&Vc[(dbi * 2 + 1) * 512 + lane * 8];
            #pragma unroll
            for (int qg = 0; qg < 2; ++qg) {
                acc_o[dbi][qg] = __builtin_amdgcn_mfma_f32_16x16x32_bf16(pa[qg][0], vb0, acc_o[dbi][qg], 0, 0, 0);
                acc_o[dbi][qg] = __builtin_amdgcn_mfma_f32_16x16x32_bf16(pa[qg][1], vb1, acc_o[dbi][qg], 0, 0, 0);
            }
        }

        __syncthreads();   // prefetch landed (covered by compute above)
    }

    // ---- finalize l (reduce the 4 quads sharing each query column) ----
    #pragma unroll
    for (int qg = 0; qg < 2; ++qg) {
        float lr = l_lane[qg];
        lr += __shfl_xor(lr, 16);
        lr += __shfl_xor(lr, 32);
        if (quad == 0) ls[w][qg][col] = 1.f / lr;   // wave-private
    }

    #pragma unroll
    for (int qg = 0; qg < 2; ++qg) {
        float4 invv = *(const float4*)&ls[w][qg][quad * 4];
        #pragma unroll
        for (int dbi = 0; dbi < 4; ++dbi)
            #pragma unroll
            for (int r = 0; r < 4; ++r) {
                int q = q0 + qbase + qg * 16 + quad * 4 + r;
                int d = dbi * 16 + col;
                float inv = (r == 0) ? invv.x : (r == 1) ? invv.y : (r == 2) ? invv.z : invv.w;
                out[((size_t)(b * SEQ + q)) * EMBED_DIM + h * 64 + d] = f2bf(acc_o[dbi][qg][r] * inv);
            }
    }
}

// ---------------------------------------------------------------------------
extern "C" void kernel_launch(void* const* d_in, const int* in_sizes, int n_in,
                              void* d_out, int out_size, void* d_ws, size_t ws_size,
                              hipStream_t stream)
{
    const float* x     = (const float*)d_in[0];
    const float* W_qkv = (const float*)d_in[1];
    const float* b_qkv = (const float*)d_in[2];
    const float* W_out = (const float*)d_in[3];
    const float* b_out = (const float*)d_in[4];
    float* out = (float*)d_out;

    const int M  = BATCH * SEQ;            // 4096
    const int D  = EMBED_DIM;              // 1024
    const int N1 = 3 * D;                  // 3072
    const size_t HE = (size_t)BATCH * NUM_HEADS * SEQ * 64;  // 4M

    ushort* xb    = (ushort*)d_ws;
    ushort* Wqb_t = xb + (size_t)M * D;
    ushort* Wob_t = Wqb_t + (size_t)D * N1;
    ushort* Qb    = Wob_t + (size_t)D * D;
    ushort* Kb    = Qb + HE;
    ushort* Vt    = Kb + HE;
    ushort* attnb = Vt + HE;

    // 0) fused prep: cast x, transpose+cast weights
    prep_all<<<5120, 256, 0, stream>>>(x, W_qkv, W_out, xb, Wqb_t, Wob_t);

    // 1) qkv projection
    gemm_qkv_mfma<<<dim3(N1 / 128, M / 128), 256, 0, stream>>>(
        xb, Wqb_t, b_qkv, Qb, Kb, Vt);

    // 2) flash attention (128-q blocks)
    attn_fused<<<dim3(16 * 32), 256, 0, stream>>>(Qb, Kb, Vt, attnb);

    // 3) output projection
    gemm_out_mfma<<<dim3(D / 128, M / 128), 256, 0, stream>>>(
        attnb, Wob_t, b_out, out);
}

// Round 12
// 196.513 us; speedup vs baseline: 1.1850x; 1.0586x over previous
//
#include <hip/hip_runtime.h>
#include <hip/hip_bf16.h>
#include <math.h>

#define EMBED_DIM 1024
#define NUM_HEADS 16
#define HEAD_DIM 64
#define BATCH 2
#define SEQ 2048

using short8  = __attribute__((ext_vector_type(8))) short;
using floatx4 = __attribute__((ext_vector_type(4))) float;

__device__ __forceinline__ ushort f2bf(float f) {
    unsigned u = __float_as_uint(f);
    u = (u + 0x7FFFu + ((u >> 16) & 1u)) >> 16;   // RNE
    return (ushort)u;
}

__device__ __forceinline__ unsigned bfpack2(float a, float b) {
    return ((__float_as_uint(a) + 0x8000u) >> 16) |
           (((__float_as_uint(b) + 0x8000u) >> 16) << 16);
}

// async global->LDS, 16B per lane; LDS dest = wave-uniform base + lane*16.
__device__ __forceinline__ void load_lds16(const ushort* g, ushort* l) {
    __builtin_amdgcn_global_load_lds(
        (const __attribute__((address_space(1))) void*)g,
        (__attribute__((address_space(3))) void*)l, 16, 0, 0);
}

// ---------------------------------------------------------------------------
// Fused prep: cast x -> bf16, transpose+cast W_qkv and W_out.
// ---------------------------------------------------------------------------
__device__ __forceinline__ void tc_tile(
    const float* __restrict__ W, ushort* __restrict__ Wt,
    int K, int N, int n0, int k0, float (*t)[65])
{
    const int c = threadIdx.x & 63, r0 = (threadIdx.x >> 6) * 16;
    #pragma unroll
    for (int r = 0; r < 16; ++r)
        t[r0 + r][c] = W[(size_t)(k0 + r0 + r) * N + n0 + c];
    __syncthreads();
    #pragma unroll
    for (int r = 0; r < 16; ++r)
        Wt[(size_t)(n0 + r0 + r) * K + k0 + c] = f2bf(t[c][r0 + r]);
}

__global__ __launch_bounds__(256) void prep_all(
    const float* __restrict__ x, const float* __restrict__ W_qkv,
    const float* __restrict__ W_out,
    ushort* __restrict__ xb, ushort* __restrict__ Wqb_t, ushort* __restrict__ Wob_t)
{
    __shared__ float t[64][65];
    const int bx = blockIdx.x;
    if (bx < 4096) {
        int i = (bx * 256 + threadIdx.x) * 4;
        float4 v = *(const float4*)&x[i];
        ushort4 o = { f2bf(v.x), f2bf(v.y), f2bf(v.z), f2bf(v.w) };
        *(ushort4*)&xb[i] = o;
    } else if (bx < 4096 + 768) {
        int b = bx - 4096;
        tc_tile(W_qkv, Wqb_t, 1024, 3072, (b % 48) * 64, (b / 48) * 64, t);
    } else {
        int b = bx - 4864;
        tc_tile(W_out, Wob_t, 1024, 1024, (b % 16) * 64, (b / 16) * 64, t);
    }
}

// ---------------------------------------------------------------------------
// bf16 MFMA GEMM core, double-buffered, m97-style ROW-LINEAR staging.
// (Round-9 lesson: fragment-ordered gather staging destroys global coalescing
// — row-linear 64B-segment staging wins despite ~3.1M LDS bank conflicts.)
// ---------------------------------------------------------------------------
#define GK 1024

__device__ __forceinline__ void gemm_core(
    const ushort* __restrict__ A, const ushort* __restrict__ Bt,
    int m0, int n0, ushort* As0, ushort* As1, ushort* Bs0, ushort* Bs1,
    floatx4 acc[4][4])
{
    const int tid  = threadIdx.x;
    const int w    = tid >> 6;
    const int lane = tid & 63;
    const int col  = lane & 15;
    const int quad = lane >> 4;
    const int wm   = w >> 1, wn = w & 1;

    #pragma unroll
    for (int i = 0; i < 4; ++i)
        #pragma unroll
        for (int j = 0; j < 4; ++j)
            acc[i][j] = (floatx4){0.f, 0.f, 0.f, 0.f};

    const int o0   = w * 2048 + lane * 16;
    const int row0 = o0 >> 6;
    const int ke0  = (o0 & 63) >> 1;
    const int loff = (w * 2048) >> 1;

    const ushort* ga = A  + (size_t)(m0 + row0) * GK + ke0;
    const ushort* gb = Bt + (size_t)(n0 + row0) * GK + ke0;

    #pragma unroll
    for (int t = 0; t < 2; ++t) {
        load_lds16(ga + (size_t)t * 16 * GK, As0 + loff + t * 512);
        load_lds16(gb + (size_t)t * 16 * GK, Bs0 + loff + t * 512);
    }
    __syncthreads();

    for (int k0 = 0; k0 < GK; k0 += 32) {
        const int cur = (k0 >> 5) & 1;
        ushort* Ac = cur ? As1 : As0;
        ushort* Bc = cur ? Bs1 : Bs0;
        ushort* An = cur ? As0 : As1;
        ushort* Bn = cur ? Bs0 : Bs1;

        if (k0 + 32 < GK) {
            #pragma unroll
            for (int t = 0; t < 2; ++t) {
                load_lds16(ga + (k0 + 32) + (size_t)t * 16 * GK, An + loff + t * 512);
                load_lds16(gb + (k0 + 32) + (size_t)t * 16 * GK, Bn + loff + t * 512);
            }
        }

        short8 af[4], bf[4];
        #pragma unroll
        for (int i = 0; i < 4; ++i)
            af[i] = *(const short8*)&Ac[(wm * 64 + i * 16 + col) * 32 + quad * 8];
        #pragma unroll
        for (int j = 0; j < 4; ++j)
            bf[j] = *(const short8*)&Bc[(wn * 64 + j * 16 + col) * 32 + quad * 8];
        #pragma unroll
        for (int i = 0; i < 4; ++i)
            #pragma unroll
            for (int j = 0; j < 4; ++j)
                acc[i][j] = __builtin_amdgcn_mfma_f32_16x16x32_bf16(af[i], bf[j], acc[i][j], 0, 0, 0);

        __syncthreads();
    }
}

// GEMM1: qkv projection; fused split/cast; V emitted transposed.
__global__ __launch_bounds__(256) void gemm_qkv_mfma(
    const ushort* __restrict__ A, const ushort* __restrict__ Bt,
    const float* __restrict__ bias,
    ushort* __restrict__ Qb, ushort* __restrict__ Kb, ushort* __restrict__ Vt)
{
    __shared__ __align__(16) ushort As[2][128 * 32];
    __shared__ __align__(16) ushort Bs[2][128 * 32];
    const int n0 = blockIdx.x * 128;
    const int m0 = blockIdx.y * 128;

    floatx4 acc[4][4];
    gemm_core(A, Bt, m0, n0, As[0], As[1], Bs[0], Bs[1], acc);

    const int lane = threadIdx.x & 63;
    const int w    = threadIdx.x >> 6;
    const int col  = lane & 15, quad = lane >> 4;
    const int wm   = w >> 1, wn = w & 1;

    #pragma unroll
    for (int j = 0; j < 4; ++j) {
        const int n = n0 + wn * 64 + j * 16 + col;
        const float bj = bias[n];
        const int part = n >> 10;
        const int h = (n >> 6) & 15;
        const int d = n & 63;
        #pragma unroll
        for (int i = 0; i < 4; ++i)
            #pragma unroll
            for (int r = 0; r < 4; ++r) {
                const int m = m0 + wm * 64 + i * 16 + quad * 4 + r;
                const int b = m >> 11, s = m & 2047;
                const int bh = b * 16 + h;
                const ushort bv = f2bf(acc[i][j][r] + bj);
                if (part == 0)      Qb[((size_t)bh * SEQ + s) * 64 + d] = bv;
                else if (part == 1) Kb[((size_t)bh * SEQ + s) * 64 + d] = bv;
                else                Vt[((size_t)bh * 64 + d) * SEQ + s] = bv;
            }
    }
}

// GEMM2: out = attn_b @ W_out + b_out -> fp32
__global__ __launch_bounds__(256) void gemm_out_mfma(
    const ushort* __restrict__ A, const ushort* __restrict__ Bt,
    const float* __restrict__ bias, float* __restrict__ out)
{
    __shared__ __align__(16) ushort As[2][128 * 32];
    __shared__ __align__(16) ushort Bs[2][128 * 32];
    const int n0 = blockIdx.x * 128;
    const int m0 = blockIdx.y * 128;

    floatx4 acc[4][4];
    gemm_core(A, Bt, m0, n0, As[0], As[1], Bs[0], Bs[1], acc);

    const int lane = threadIdx.x & 63;
    const int w    = threadIdx.x >> 6;
    const int col  = lane & 15, quad = lane >> 4;
    const int wm   = w >> 1, wn = w & 1;

    #pragma unroll
    for (int j = 0; j < 4; ++j) {
        const int n = n0 + wn * 64 + j * 16 + col;
        const float bj = bias[n];
        #pragma unroll
        for (int i = 0; i < 4; ++i)
            #pragma unroll
            for (int r = 0; r < 4; ++r) {
                const int m = m0 + wm * 64 + i * 16 + quad * 4 + r;
                out[(size_t)m * EMBED_DIM + n] = acc[i][j][r] + bj;
            }
    }
}

// ---------------------------------------------------------------------------
// Flash attention, bf16 MFMA. 64-query block (grid 1024, 4 blocks/CU),
// 16 queries per wave, S^T softmax, Q in registers, LDS = 40960 B exactly.
// P written directly in PV A-fragment order (wave-private 2 KB):
//   key k = kb*16+quad*4+r -> fragment kh=kb>>1,
//   lane' = col + 16*((kb&1)*2+(quad>>1)), j = (quad&1)*4+r.
// Diagonal mask is TILE-LOCAL on both sides: key kb*16+quad*4+r vs query
// myq = w*16+col  (round-11 bug: compared against col only — waves 1-3
// zeroed valid keys).
// l: butterfly shfl_xor(16,32) all-reduce + ds_bpermute transpose. LPT order.
// ---------------------------------------------------------------------------
__global__ __launch_bounds__(256) void attn_fused(
    const ushort* __restrict__ Qb, const ushort* __restrict__ Kb,
    const ushort* __restrict__ Vt, ushort* __restrict__ out)
{
    const int id = blockIdx.x;
    const int qt = 31 - (id >> 5);          // 64-q tiles, reversed (LPT)
    const int bh = id & 31;
    const int b  = bh >> 4, h = bh & 15;
    const int q0 = qt * 64;

    __shared__ __align__(16) ushort Ks[2][8 * 512];   // 16 KB dbuf
    __shared__ __align__(16) ushort Vs[2][8 * 512];   // 16 KB dbuf
    __shared__ __align__(16) ushort Ps[4 * 1024];     // 8 KB, A-frag order

    const int tid  = threadIdx.x;
    const int w    = tid >> 6;
    const int lane = tid & 63;
    const int col  = lane & 15;
    const int quad = lane >> 4;

    // ---- Q fragments -> registers (queries q0 + w*16 + col) ----
    short8 qf[2];
    #pragma unroll
    for (int kh = 0; kh < 2; ++kh)
        qf[kh] = *(const short8*)&Qb[((size_t)bh * SEQ + q0 + w * 16 + col) * 64
                                     + kh * 32 + quad * 8];

    // ---- K/V staging pointers: wave w stages chunks 2w, 2w+1 ----
    const ushort* kg[2];
    const ushort* vg[2];
    #pragma unroll
    for (int t = 0; t < 2; ++t) {
        kg[t] = Kb + (size_t)bh * SEQ * 64 + (size_t)(w * 16 + col) * 64 + t * 32 + quad * 8;
        vg[t] = Vt + (size_t)bh * 64 * SEQ + (size_t)(w * 16 + col) * SEQ + t * 32 + quad * 8;
    }

    // prologue: stage tile 0 into buffer 0
    #pragma unroll
    for (int t = 0; t < 2; ++t) {
        load_lds16(kg[t], &Ks[0][(2 * w + t) * 512]);
        load_lds16(vg[t], &Vs[0][(2 * w + t) * 512]);
        kg[t] += 64 * 64;
        vg[t] += 64;
    }
    __syncthreads();

    floatx4 acc_o[4];
    #pragma unroll
    for (int dbi = 0; dbi < 4; ++dbi) acc_o[dbi] = (floatx4){0.f, 0.f, 0.f, 0.f};
    float l_lane = 0.f;                      // partial l for query col (wave-local)

    ushort* Pw = &Ps[w * 1024];              // wave-private P region
    const int pq = (quad & 1) * 4;           // j base within dest 16B
    const int myq = w * 16 + col;            // tile-local query in S^T

    for (int kt = 0; kt <= qt; ++kt) {
        const int cur = kt & 1;
        const ushort* Kc = Ks[cur];
        const ushort* Vc = Vs[cur];

        if (kt < qt) {   // issue-early prefetch into the other buffer
            ushort* Kn = (ushort*)Ks[cur ^ 1];
            ushort* Vn = (ushort*)Vs[cur ^ 1];
            #pragma unroll
            for (int t = 0; t < 2; ++t) {
                load_lds16(kg[t], &Kn[(2 * w + t) * 512]);
                load_lds16(vg[t], &Vn[(2 * w + t) * 512]);
                kg[t] += 64 * 64;
                vg[t] += 64;
            }
        }

        // ---- S^T = K Q^T : 64 keys x 16 queries per wave ----
        floatx4 st[4];
        #pragma unroll
        for (int kb = 0; kb < 4; ++kb) {
            short8 k0f = *(const short8*)&Kc[(kb * 2 + 0) * 512 + lane * 8];
            short8 k1f = *(const short8*)&Kc[(kb * 2 + 1) * 512 + lane * 8];
            floatx4 z = (floatx4){0.f, 0.f, 0.f, 0.f};
            z = __builtin_amdgcn_mfma_f32_16x16x32_bf16(k0f, qf[0], z, 0, 0, 0);
            z = __builtin_amdgcn_mfma_f32_16x16x32_bf16(k1f, qf[1], z, 0, 0, 0);
            st[kb] = z;   // lane: query col; regs: keys kb*16+quad*4+r
        }

        // ---- p = exp(s/8); write P directly in A-fragment order ----
        if (kt == qt) {   // diagonal tile: mask tile-local key > tile-local query
            #pragma unroll
            for (int kb = 0; kb < 4; ++kb) {
                const int kbase = kb * 16 + quad * 4;
                float p[4];
                #pragma unroll
                for (int r = 0; r < 4; ++r) {
                    float e = __expf(st[kb][r] * 0.125f);
                    p[r] = (kbase + r > myq) ? 0.f : e;
                    l_lane += p[r];
                }
                uint2 u = { bfpack2(p[0], p[1]), bfpack2(p[2], p[3]) };
                *(uint2*)&Pw[(kb >> 1) * 512 + (col + 16 * ((kb & 1) * 2 + (quad >> 1))) * 8 + pq] = u;
            }
        } else {
            #pragma unroll
            for (int kb = 0; kb < 4; ++kb) {
                float p[4];
                #pragma unroll
                for (int r = 0; r < 4; ++r) {
                    p[r] = __expf(st[kb][r] * 0.125f);
                    l_lane += p[r];
                }
                uint2 u = { bfpack2(p[0], p[1]), bfpack2(p[2], p[3]) };
                *(uint2*)&Pw[(kb >> 1) * 512 + (col + 16 * ((kb & 1) * 2 + (quad >> 1))) * 8 + pq] = u;
            }
        }

        // ---- O += P V  (A-frag read: trivial, conflict-free) ----
        short8 pa0 = *(const short8*)&Pw[0 * 512 + lane * 8];
        short8 pa1 = *(const short8*)&Pw[1 * 512 + lane * 8];
        #pragma unroll
        for (int dbi = 0; dbi < 4; ++dbi) {
            short8 vb0 = *(const short8*)&Vc[(dbi * 2 + 0) * 512 + lane * 8];
            short8 vb1 = *(const short8*)&Vc[(dbi * 2 + 1) * 512 + lane * 8];
            acc_o[dbi] = __builtin_amdgcn_mfma_f32_16x16x32_bf16(pa0, vb0, acc_o[dbi], 0, 0, 0);
            acc_o[dbi] = __builtin_amdgcn_mfma_f32_16x16x32_bf16(pa1, vb1, acc_o[dbi], 0, 0, 0);
        }

        __syncthreads();   // prefetch landed (covered by compute above)
    }

    // ---- finalize l: butterfly all-reduce over quads, bpermute transpose ----
    l_lane += __shfl_xor(l_lane, 16);
    l_lane += __shfl_xor(l_lane, 32);        // every lane: L[query = col]
    const float inv = 1.f / l_lane;
    float invq[4];
    #pragma unroll
    for (int r = 0; r < 4; ++r) {
        int iv = __builtin_amdgcn_ds_bpermute((quad * 4 + r) << 2, __float_as_int(inv));
        invq[r] = __int_as_float(iv);        // inv_l for query quad*4+r
    }

    #pragma unroll
    for (int dbi = 0; dbi < 4; ++dbi)
        #pragma unroll
        for (int r = 0; r < 4; ++r) {
            int q = q0 + w * 16 + quad * 4 + r;
            int d = dbi * 16 + col;
            out[((size_t)(b * SEQ + q)) * EMBED_DIM + h * 64 + d] = f2bf(acc_o[dbi][r] * invq[r]);
        }
}

// ---------------------------------------------------------------------------
extern "C" void kernel_launch(void* const* d_in, const int* in_sizes, int n_in,
                              void* d_out, int out_size, void* d_ws, size_t ws_size,
                              hipStream_t stream)
{
    const float* x     = (const float*)d_in[0];
    const float* W_qkv = (const float*)d_in[1];
    const float* b_qkv = (const float*)d_in[2];
    const float* W_out = (const float*)d_in[3];
    const float* b_out = (const float*)d_in[4];
    float* out = (float*)d_out;

    const int M  = BATCH * SEQ;            // 4096
    const int D  = EMBED_DIM;              // 1024
    const int N1 = 3 * D;                  // 3072
    const size_t HE = (size_t)BATCH * NUM_HEADS * SEQ * 64;  // 4M

    ushort* xb    = (ushort*)d_ws;
    ushort* Wqb_t = xb + (size_t)M * D;
    ushort* Wob_t = Wqb_t + (size_t)D * N1;
    ushort* Qb    = Wob_t + (size_t)D * D;
    ushort* Kb    = Qb + HE;
    ushort* Vt    = Kb + HE;
    ushort* attnb = Vt + HE;

    // 0) fused prep: cast x, transpose+cast weights
    prep_all<<<5120, 256, 0, stream>>>(x, W_qkv, W_out, xb, Wqb_t, Wob_t);

    // 1) qkv projection
    gemm_qkv_mfma<<<dim3(N1 / 128, M / 128), 256, 0, stream>>>(
        xb, Wqb_t, b_qkv, Qb, Kb, Vt);

    // 2) flash attention (64-q blocks, 4 blocks/CU)
    attn_fused<<<dim3(32 * 32), 256, 0, stream>>>(Qb, Kb, Vt, attnb);

    // 3) output projection
    gemm_out_mfma<<<dim3(D / 128, M / 128), 256, 0, stream>>>(
        attnb, Wob_t, b_out, out);
}